// Round 3
// baseline (5280.242 us; speedup 1.0000x reference)
//
#include <hip/hip_runtime.h>

#define B_ 16384
#define T_ 80
#define D_ 12
#define H_ 128
#define BT 32      // batch rows per block
#define NTH 256
#define NBLK (B_ / BT)   // 512

__device__ __forceinline__ float sigm(float x){ return 1.f / (1.f + __expf(-x)); }
__device__ __forceinline__ float tanhc(float x){
  x = fminf(fmaxf(x, -15.f), 15.f);
  float e = __expf(2.f * x);
  return (e - 1.f) / (e + 1.f);
}

// ---------------- K0a: per-step mask denominators ----------------
__global__ void k_denom(const float* __restrict__ masks, float* __restrict__ denomInv) {
  int t = blockIdx.x, tid = threadIdx.x;
  float s = 0.f;
  for (int b = tid; b < B_; b += NTH) {
    const float4* p = (const float4*)(masks + ((size_t)b * T_ + t) * D_);
    float4 a = p[0], c = p[1], d = p[2];
    s += a.x + a.y + a.z + a.w + c.x + c.y + c.z + c.w + d.x + d.y + d.z + d.w;
  }
  __shared__ float r[NTH];
  r[tid] = s; __syncthreads();
  for (int st = NTH / 2; st > 0; st >>= 1) { if (tid < st) r[tid] += r[tid + st]; __syncthreads(); }
  if (tid == 0) denomInv[t] = 1.f / (r[0] + 1e-5f);
}

// ---------------- K0b: repack gate weights (gate-interleaved, k-major, f32) ----------------
__global__ void k_pack(const float* __restrict__ W_ih, const float* __restrict__ b_ih,
                       const float* __restrict__ W_hh, const float* __restrict__ b_hh,
                       float* __restrict__ Wp_hh, float* __restrict__ Wp_ih,
                       float* __restrict__ bias_pk) {
  int idx = blockIdx.x * NTH + threadIdx.x;
  if (idx < 65536) {                         // Wp_hh[k][j][g] <- W_hh[(g*128+j)*128 + k]
    int k = idx >> 9, rem = idx & 511, j = rem >> 2, g = rem & 3;
    Wp_hh[idx] = W_hh[(g * 128 + j) * 128 + k];
  } else if (idx < 65536 + 12288) {          // Wp_ih[k][j][g] <- W_ih[(g*128+j)*24 + k]
    int e = idx - 65536;
    int k = e >> 9, rem = e & 511, j = rem >> 2, g = rem & 3;
    Wp_ih[e] = W_ih[(g * 128 + j) * 24 + k];
  } else if (idx < 65536 + 12288 + 512) {    // bias_pk[j][g] = b_ih + b_hh
    int e = idx - 65536 - 12288, j = e >> 2, g = e & 3;
    bias_pk[e] = b_ih[g * 128 + j] + b_hh[g * 128 + j];
  }
}

// ---------------- K1: main recurrence ----------------
#define GUP(HV, BB) { float _h = (HV); \
  acc[BB].x = fmaf(_h, wi, acc[BB].x); \
  acc[BB].y = fmaf(_h, wf, acc[BB].y); \
  acc[BB].z = fmaf(_h, wg, acc[BB].z); \
  acc[BB].w = fmaf(_h, wo, acc[BB].w); }

#define GUP16(SRC) { \
  const float4 hA = *(const float4*)((SRC)); \
  const float4 hB = *(const float4*)((SRC) + 4); \
  const float4 hC = *(const float4*)((SRC) + 8); \
  const float4 hD = *(const float4*)((SRC) + 12); \
  GUP(hA.x, 0)  GUP(hA.y, 1)  GUP(hA.z, 2)  GUP(hA.w, 3) \
  GUP(hB.x, 4)  GUP(hB.y, 5)  GUP(hB.z, 6)  GUP(hB.w, 7) \
  GUP(hC.x, 8)  GUP(hC.y, 9)  GUP(hC.z, 10) GUP(hC.w, 11) \
  GUP(hD.x, 12) GUP(hD.y, 13) GUP(hD.z, 14) GUP(hD.w, 15) }

__global__ __launch_bounds__(NTH, 2) void k_main(
    const float* __restrict__ values, const float* __restrict__ masks, const float* __restrict__ deltas,
    const float* __restrict__ td_h_W, const float* __restrict__ td_h_b,
    const float* __restrict__ td_x_W, const float* __restrict__ td_x_b,
    const float* __restrict__ hist_W, const float* __restrict__ hist_b,
    const float* __restrict__ feat_W, const float* __restrict__ feat_b,
    const float* __restrict__ wc_W, const float* __restrict__ wc_b,
    const float* __restrict__ out_W, const float* __restrict__ out_b,
    const float* __restrict__ denomInv, const float* __restrict__ bias_pk,
    const float* __restrict__ Wp_hh, const float* __restrict__ Wp_ih,
    float* __restrict__ blockLoss, float* __restrict__ out_pred, float* __restrict__ out_imp) {

  __shared__ float h_t[2][H_][36];                 // k-major, padded (36) for bank spread
  __shared__ float x_s[BT][D_], m_s[BT][D_], d_s[BT][D_], xc_s[BT][D_], gx_s[BT][D_];
  __shared__ float mt_s[D_][BT], cct_s[D_][BT];    // transposed for gate phase
  __shared__ float tdhW_s[H_][D_], tdhb_s[H_];
  __shared__ float histW_s[D_][H_], histb_s[D_];
  __shared__ float featW_s[D_][D_], featb_s[D_];
  __shared__ float wcW_s[D_][2 * D_], wcb_s[D_];
  __shared__ float tdxd_s[D_], tdxb_s[D_];
  __shared__ float outW_s[H_];
  __shared__ float outb_s;
  __shared__ float red_s[NTH];

  const int tid = threadIdx.x;
  const int bs = blockIdx.x * BT;

  // ---- one-time: small weights -> LDS, zero h ----
  for (int idx = tid; idx < H_ * D_; idx += NTH) ((float*)tdhW_s)[idx] = td_h_W[idx];
  for (int idx = tid; idx < D_ * H_; idx += NTH) ((float*)histW_s)[idx] = hist_W[idx];
  if (tid < H_) { tdhb_s[tid] = td_h_b[tid]; outW_s[tid] = out_W[tid]; }
  for (int idx = tid; idx < D_ * D_; idx += NTH)
    ((float*)featW_s)[idx] = ((idx / D_) == (idx % D_)) ? 0.f : feat_W[idx];
  for (int idx = tid; idx < D_ * 2 * D_; idx += NTH)   // 288 > NTH: MUST loop (was the bug)
    ((float*)wcW_s)[idx] = wc_W[idx];
  if (tid < D_) {
    histb_s[tid] = hist_b[tid]; featb_s[tid] = feat_b[tid];
    wcb_s[tid] = wc_b[tid];     tdxb_s[tid] = td_x_b[tid];
    tdxd_s[tid] = td_x_W[tid * D_ + tid];
  }
  if (tid == 0) outb_s = out_b[0];
  for (int idx = tid; idx < H_ * 36; idx += NTH) ((float*)h_t[0])[idx] = 0.f;

  float c_st[16];
  #pragma unroll
  for (int b = 0; b < 16; ++b) c_st[b] = 0.f;
  float lossAcc = 0.f;
  const int jj = tid & 127, bgrp = tid >> 7, bb0 = bgrp << 4;
  const float4 bv = *(const float4*)(bias_pk + 4 * jj);   // gate biases, constant over T
  int cur = 0;
  __syncthreads();

  for (int t = 0; t < T_; ++t) {
    const float dInv = denomInv[t];
    // ---- S0: stage x, m, d tiles (float4) ----
    for (int idx = tid; idx < 288; idx += NTH) {
      int a = idx / 96, r = idx % 96, b = r / 3, q = r % 3;
      const float* src = (a == 0) ? values : (a == 1) ? masks : deltas;
      float4 v = *(const float4*)(src + ((size_t)(bs + b) * T_ + t) * D_ + q * 4);
      if (a == 0)      *(float4*)&x_s[b][q * 4] = v;
      else if (a == 1) { *(float4*)&m_s[b][q * 4] = v;
                         mt_s[q * 4 + 0][b] = v.x; mt_s[q * 4 + 1][b] = v.y;
                         mt_s[q * 4 + 2][b] = v.z; mt_s[q * 4 + 3][b] = v.w; }
      else             *(float4*)&d_s[b][q * 4] = v;
    }
    __syncthreads();

    // ---- S1: gamma_h decay of h (in place), gamma_x ----
    #pragma unroll
    for (int p = 0; p < 16; ++p) {
      int pi = p * NTH + tid, b = pi & 31, j = pi >> 5;
      float a = tdhb_s[j];
      #pragma unroll
      for (int k = 0; k < D_; ++k) a = fmaf(d_s[b][k], tdhW_s[j][k], a);
      h_t[cur][j][b] *= __expf(-fmaxf(a, 0.f));
    }
    for (int idx = tid; idx < BT * D_; idx += NTH) {
      int b = idx & 31, i = idx >> 5;
      gx_s[b][i] = __expf(-fmaxf(fmaf(d_s[b][i], tdxd_s[i], tdxb_s[i]), 0.f));
    }
    __syncthreads();

    // ---- S2: x_h = h @ hist_W.T + b; loss1; x_c ----
    float xh_reg[2];
    #pragma unroll
    for (int r = 0; r < 2; ++r) {
      int idx = tid + r * NTH;
      if (idx < BT * D_) {
        int b = idx & 31, i = idx >> 5;
        float a0 = 0.f, a1 = 0.f, a2 = 0.f, a3 = 0.f;
        #pragma unroll 4
        for (int k = 0; k < H_; k += 4) {
          a0 = fmaf(h_t[cur][k    ][b], histW_s[i][k    ], a0);
          a1 = fmaf(h_t[cur][k + 1][b], histW_s[i][k + 1], a1);
          a2 = fmaf(h_t[cur][k + 2][b], histW_s[i][k + 2], a2);
          a3 = fmaf(h_t[cur][k + 3][b], histW_s[i][k + 3], a3);
        }
        float xh = a0 + a1 + a2 + a3 + histb_s[i];
        xh_reg[r] = xh;
        float xv = x_s[b][i], mv = m_s[b][i];
        lossAcc = fmaf(fabsf(xv - xh) * mv, dInv, lossAcc);
        xc_s[b][i] = fmaf(mv, xv - xh, xh);
      }
    }
    __syncthreads();

    // ---- S3/S4: z_h, alpha, c_h, c_c, loss2+3 ----
    #pragma unroll
    for (int r = 0; r < 2; ++r) {
      int idx = tid + r * NTH;
      if (idx < BT * D_) {
        int b = idx & 31, i = idx >> 5;
        float zh = featb_s[i];
        #pragma unroll
        for (int k = 0; k < D_; ++k) zh = fmaf(xc_s[b][k], featW_s[i][k], zh);
        float xv = x_s[b][i], mv = m_s[b][i];
        lossAcc = fmaf(fabsf(xv - zh) * mv, dInv, lossAcc);
        float al = wcb_s[i];
        #pragma unroll
        for (int k = 0; k < D_; ++k) {
          al = fmaf(gx_s[b][k], wcW_s[i][k], al);
          al = fmaf(m_s[b][k], wcW_s[i][D_ + k], al);
        }
        float ch = fmaf(al, zh - xh_reg[r], xh_reg[r]);
        lossAcc = fmaf(fabsf(xv - ch) * mv, dInv, lossAcc);
        float cc = fmaf(mv, xv - ch, ch);
        cct_s[i][b] = cc;
      }
    }
    __syncthreads();

    // ---- imputation store (float4, coalesced) ----
    if (tid < 96) {
      int b = tid / 3, q = tid % 3;
      float4 v = make_float4(cct_s[q * 4 + 0][b], cct_s[q * 4 + 1][b],
                             cct_s[q * 4 + 2][b], cct_s[q * 4 + 3][b]);
      *(float4*)(out_imp + ((size_t)(bs + b) * T_ + t) * D_ + q * 4) = v;
    }

    // ---- S5: gates + LSTM pointwise; h_new into other buffer ----
    {
      float4 acc[16];
      #pragma unroll
      for (int b = 0; b < 16; ++b) acc[b] = make_float4(0.f, 0.f, 0.f, 0.f);
      #pragma unroll
      for (int k = 0; k < D_; ++k) {                    // c_c part
        float4 w = *(const float4*)(Wp_ih + ((k * 128 + jj) << 2));
        float wi = w.x, wf = w.y, wg = w.z, wo = w.w;
        GUP16(&cct_s[k][bb0]);
      }
      #pragma unroll
      for (int k = 0; k < D_; ++k) {                    // m part
        float4 w = *(const float4*)(Wp_ih + (((k + D_) * 128 + jj) << 2));
        float wi = w.x, wf = w.y, wg = w.z, wo = w.w;
        GUP16(&mt_s[k][bb0]);
      }
      #pragma unroll 4
      for (int k = 0; k < H_; ++k) {                    // h part (dominant)
        float4 w = *(const float4*)(Wp_hh + ((k * 128 + jj) << 2));
        float wi = w.x, wf = w.y, wg = w.z, wo = w.w;
        GUP16(&h_t[cur][k][bb0]);
      }
      #pragma unroll
      for (int b = 0; b < 16; ++b) {
        float gi = sigm(acc[b].x + bv.x);
        float gf = sigm(acc[b].y + bv.y);
        float gg = tanhc(acc[b].z + bv.z);
        float go = sigm(acc[b].w + bv.w);
        c_st[b] = fmaf(gf, c_st[b], gi * gg);
        h_t[cur ^ 1][jj][bb0 + b] = go * tanhc(c_st[b]);
      }
    }
    __syncthreads();
    cur ^= 1;
  }

  // ---- predictions ----
  if (tid < BT) {
    int b = tid;
    float a0 = 0.f, a1 = 0.f, a2 = 0.f, a3 = 0.f;
    #pragma unroll 4
    for (int k = 0; k < H_; k += 4) {
      a0 = fmaf(h_t[cur][k    ][b], outW_s[k    ], a0);
      a1 = fmaf(h_t[cur][k + 1][b], outW_s[k + 1], a1);
      a2 = fmaf(h_t[cur][k + 2][b], outW_s[k + 2], a2);
      a3 = fmaf(h_t[cur][k + 3][b], outW_s[k + 3], a3);
    }
    out_pred[bs + b] = sigm(a0 + a1 + a2 + a3 + outb_s);
  }

  // ---- block loss reduce ----
  red_s[tid] = lossAcc;
  __syncthreads();
  for (int s = NTH / 2; s > 0; s >>= 1) { if (tid < s) red_s[tid] += red_s[tid + s]; __syncthreads(); }
  if (tid == 0) blockLoss[blockIdx.x] = red_s[0];
}

// ---------------- K2: final loss ----------------
__global__ void k_final(const float* __restrict__ blockLoss, float* __restrict__ out_loss) {
  __shared__ float r[NTH];
  int tid = threadIdx.x;
  r[tid] = blockLoss[tid] + blockLoss[tid + NTH];
  __syncthreads();
  for (int s = NTH / 2; s > 0; s >>= 1) { if (tid < s) r[tid] += r[tid + s]; __syncthreads(); }
  if (tid == 0) out_loss[0] = r[0] * (1.f / (float)T_);
}

extern "C" void kernel_launch(void* const* d_in, const int* in_sizes, int n_in,
                              void* d_out, int out_size, void* d_ws, size_t ws_size,
                              hipStream_t stream) {
  const float* values = (const float*)d_in[0];
  const float* masks  = (const float*)d_in[1];
  const float* deltas = (const float*)d_in[2];
  const float* td_h_W = (const float*)d_in[3];
  const float* td_h_b = (const float*)d_in[4];
  const float* td_x_W = (const float*)d_in[5];
  const float* td_x_b = (const float*)d_in[6];
  const float* hist_W = (const float*)d_in[7];
  const float* hist_b = (const float*)d_in[8];
  const float* feat_W = (const float*)d_in[9];
  const float* feat_b = (const float*)d_in[10];
  const float* wc_W   = (const float*)d_in[11];
  const float* wc_b   = (const float*)d_in[12];
  const float* W_ih   = (const float*)d_in[13];
  const float* b_ih   = (const float*)d_in[14];
  const float* W_hh   = (const float*)d_in[15];
  const float* b_hh   = (const float*)d_in[16];
  const float* out_W  = (const float*)d_in[17];
  const float* out_b  = (const float*)d_in[18];

  float* ws_f      = (float*)d_ws;
  float* denomInv  = ws_f;          // 80 f32
  float* bias_pk   = ws_f + 128;    // 512 f32
  float* blockLoss = ws_f + 1024;   // 512 f32
  float* Wp_hh     = ws_f + 2048;   // 65536 f32
  float* Wp_ih     = Wp_hh + 65536; // 12288 f32

  float* out_f = (float*)d_out;     // [loss(1) | predictions(B) | imputations(B*T*D)]

  k_denom<<<T_, NTH, 0, stream>>>(masks, denomInv);
  k_pack<<<306, NTH, 0, stream>>>(W_ih, b_ih, W_hh, b_hh, Wp_hh, Wp_ih, bias_pk);
  k_main<<<NBLK, NTH, 0, stream>>>(values, masks, deltas, td_h_W, td_h_b, td_x_W, td_x_b,
                                   hist_W, hist_b, feat_W, feat_b, wc_W, wc_b,
                                   out_W, out_b, denomInv, bias_pk, Wp_hh, Wp_ih,
                                   blockLoss, out_f + 1, out_f + 1 + B_);
  k_final<<<1, NTH, 0, stream>>>(blockLoss, out_f);
}

// Round 4
// 903.148 us; speedup vs baseline: 5.8465x; 5.8465x over previous
//
#include <hip/hip_runtime.h>

#define B_ 16384
#define T_ 80
#define D_ 12
#define H_ 128
#define BT 32            // batch rows per block
#define NTH 512          // 8 waves
#define NBLK (B_ / BT)   // 512
#define AK 168           // A-tile row stride in bf16 elems (16B-aligned: 336B)

typedef unsigned short us_t;
typedef unsigned int u32_t;
typedef short bf16x8 __attribute__((ext_vector_type(8)));
typedef float f32x4 __attribute__((ext_vector_type(4)));

__device__ __forceinline__ us_t f2bf(float f){
  u32_t x = __float_as_uint(f);
  return (us_t)((x + 0x7FFFu + ((x >> 16) & 1u)) >> 16);   // RNE
}
__device__ __forceinline__ float bf2f(us_t u){
  union { u32_t i; float f; } v; v.i = ((u32_t)u) << 16; return v.f;
}
__device__ __forceinline__ float sigm(float x){ return 1.f / (1.f + __expf(-x)); }
__device__ __forceinline__ float tanhc(float x){
  x = fminf(fmaxf(x, -15.f), 15.f);
  float e = __expf(2.f * x);
  return (e - 1.f) / (e + 1.f);
}

// ---------------- K0a: per-step mask denominators ----------------
__global__ void k_denom(const float* __restrict__ masks, float* __restrict__ denomInv) {
  int t = blockIdx.x, tid = threadIdx.x;
  float s = 0.f;
  for (int b = tid; b < B_; b += 256) {
    const float4* p = (const float4*)(masks + ((size_t)b * T_ + t) * D_);
    float4 a = p[0], c = p[1], d = p[2];
    s += a.x + a.y + a.z + a.w + c.x + c.y + c.z + c.w + d.x + d.y + d.z + d.w;
  }
  __shared__ float r[256];
  r[tid] = s; __syncthreads();
  for (int st = 128; st > 0; st >>= 1) { if (tid < st) r[tid] += r[tid + st]; __syncthreads(); }
  if (tid == 0) denomInv[t] = 1.f / (r[0] + 1e-5f);
}

// ---------------- K0b: pack weights into per-lane MFMA B-fragments (bf16) ----------------
// Wb frag (g,w-wave,kc): lane l holds col n = g*128 + w*16 + (l&15), k = kc*32 + (l>>4)*8 + i
// combined K: k<12 -> c_c (W_ih[:, k]), 12..23 -> m (W_ih[:, k]), 24..151 -> h (W_hh[:, k-24]), pad 0
__global__ void k_pack(const float* __restrict__ W_ih, const float* __restrict__ b_ih,
                       const float* __restrict__ W_hh, const float* __restrict__ b_hh,
                       const float* __restrict__ hist_W,
                       us_t* __restrict__ Wb, us_t* __restrict__ histB,
                       float* __restrict__ bias_pk) {
  int idx = blockIdx.x * 256 + threadIdx.x;
  if (idx < 81920) {
    int i = idx & 7, lane = (idx >> 3) & 63, rest = idx >> 9;
    int kc = rest % 5; rest /= 5;
    int g = rest & 3, w = rest >> 2;
    int n = g * 128 + w * 16 + (lane & 15);
    int k = kc * 32 + ((lane >> 4) << 3) + i;
    float v = 0.f;
    if (k < 24) v = W_ih[n * 24 + k];
    else if (k < 152) v = W_hh[n * 128 + (k - 24)];
    Wb[idx] = f2bf(v);
  } else if (idx < 81920 + 2048) {
    int e = idx - 81920;
    int i = e & 7, lane = (e >> 3) & 63, kc = e >> 9;
    int col = lane & 15, k = kc * 32 + ((lane >> 4) << 3) + i;
    histB[e] = f2bf(col < 12 ? hist_W[col * 128 + k] : 0.f);
  } else if (idx < 81920 + 2048 + 512) {
    int e = idx - 83968;
    bias_pk[e] = b_ih[e] + b_hh[e];
  }
}

// ---------------- K1: main recurrence (MFMA gate path) ----------------
__global__ __launch_bounds__(NTH) void k_main(
    const float* __restrict__ values, const float* __restrict__ masks, const float* __restrict__ deltas,
    const float* __restrict__ td_h_W, const float* __restrict__ td_h_b,
    const float* __restrict__ td_x_W, const float* __restrict__ td_x_b,
    const float* __restrict__ hist_b,
    const float* __restrict__ feat_W, const float* __restrict__ feat_b,
    const float* __restrict__ wc_W, const float* __restrict__ wc_b,
    const float* __restrict__ out_W, const float* __restrict__ out_b,
    const float* __restrict__ denomInv, const float* __restrict__ bias_pk,
    const us_t* __restrict__ Wb, const us_t* __restrict__ histB,
    float* __restrict__ blockLoss, float* __restrict__ out_pred, float* __restrict__ out_imp) {

  __shared__ __align__(16) us_t A_s[2][BT][AK];   // bf16 {c_c[0:12], m[12:24], h[24:152], pad}
  __shared__ float x_s[BT][13], m_s[BT][13], d_s[BT][13];
  __shared__ float gx_s[BT][13], xc_s[BT][13], cct_s[BT][13], xh_s[BT][13];
  __shared__ float tdhW_s[H_][D_], tdhb_s[H_];
  __shared__ float featW_s[D_][D_], featb_s[D_];
  __shared__ float wcW_s[D_][2 * D_], wcb_s[D_];
  __shared__ float tdxd_s[D_], tdxb_s[D_];
  __shared__ float outW_s[H_];
  __shared__ float outb_s;
  __shared__ float red_s[NTH];

  const int tid = threadIdx.x;
  const int bs = blockIdx.x * BT;
  const int w = tid >> 6, l = tid & 63;
  const int lr = l & 15, lg = l >> 4;      // fragment row/col index, k-group

  // ---- one-time: small weights -> LDS, zero A tiles ----
  for (int i2 = tid; i2 < H_ * D_; i2 += NTH) ((float*)tdhW_s)[i2] = td_h_W[i2];
  if (tid < H_) { tdhb_s[tid] = td_h_b[tid]; outW_s[tid] = out_W[tid]; }
  if (tid < D_ * D_) ((float*)featW_s)[tid] = ((tid / D_) == (tid % D_)) ? 0.f : feat_W[tid];
  if (tid < D_ * 2 * D_) ((float*)wcW_s)[tid] = wc_W[tid];    // 288 < 512: single pass ok
  if (tid < D_) {
    featb_s[tid] = feat_b[tid]; wcb_s[tid] = wc_b[tid];
    tdxb_s[tid] = td_x_b[tid];  tdxd_s[tid] = td_x_W[tid * D_ + tid];
  }
  if (tid == 0) outb_s = out_b[0];
  for (int i2 = tid; i2 < 2 * BT * AK; i2 += NTH) ((us_t*)A_s)[i2] = 0;

  // ---- persistent B-fragments in registers ----
  bf16x8 bq[4][5];
  #pragma unroll
  for (int g = 0; g < 4; ++g)
    #pragma unroll
    for (int kc = 0; kc < 5; ++kc)
      bq[g][kc] = *(const bf16x8*)(Wb + (size_t)((((w * 4 + g) * 5 + kc) * 64 + l) << 3));
  bf16x8 hb[4];
  #pragma unroll
  for (int kc = 0; kc < 4; ++kc)
    hb[kc] = *(const bf16x8*)(histB + (size_t)(((kc * 64) + l) << 3));
  float bj[4];
  #pragma unroll
  for (int g = 0; g < 4; ++g) bj[g] = bias_pk[g * 128 + w * 16 + lr];
  const float hbias = hist_b[lr < 12 ? lr : 0];

  float c_st[2][4] = {{0.f,0.f,0.f,0.f},{0.f,0.f,0.f,0.f}};
  float lossAcc = 0.f;
  int cur = 0;
  __syncthreads();

  for (int t = 0; t < T_; ++t) {
    const float dInv = denomInv[t];

    // ---- S0: stage x,m,d (float4); m also -> A bf16 ----
    if (tid < 288) {
      int a = tid / 96, r = tid % 96, b = r / 3, q = r % 3;
      const float* src = (a == 0) ? values : (a == 1) ? masks : deltas;
      float4 v = *(const float4*)(src + ((size_t)(bs + b) * T_ + t) * D_ + q * 4);
      if (a == 0)      *(float4*)&x_s[b][q * 4] = v;
      else if (a == 1) {
        *(float4*)&m_s[b][q * 4] = v;
        A_s[cur][b][12 + q * 4 + 0] = f2bf(v.x);
        A_s[cur][b][12 + q * 4 + 1] = f2bf(v.y);
        A_s[cur][b][12 + q * 4 + 2] = f2bf(v.z);
        A_s[cur][b][12 + q * 4 + 3] = f2bf(v.w);
      } else           *(float4*)&d_s[b][q * 4] = v;
    }
    __syncthreads();

    // ---- S1: gamma_h decay of h (bf16 RMW in A), gamma_x ----
    #pragma unroll
    for (int p = 0; p < 8; ++p) {
      int pi = p * NTH + tid, b = pi & 31, j = pi >> 5;
      float a = tdhb_s[j];
      #pragma unroll
      for (int k = 0; k < D_; ++k) a = fmaf(d_s[b][k], tdhW_s[j][k], a);
      float gh = __expf(-fmaxf(a, 0.f));
      us_t* hp = &A_s[cur][b][24 + j];
      *hp = f2bf(bf2f(*hp) * gh);
    }
    if (tid < BT * D_) {
      int b = tid & 31, i = tid >> 5;
      gx_s[b][i] = __expf(-fmaxf(fmaf(d_s[b][i], tdxd_s[i], tdxb_s[i]), 0.f));
    }
    __syncthreads();

    // ---- S2: x_h = h @ hist_W.T via MFMA (waves 0,1) ----
    if (w < 2) {
      f32x4 xacc = {0.f, 0.f, 0.f, 0.f};
      #pragma unroll
      for (int kc = 0; kc < 4; ++kc) {
        const bf16x8 a = *(const bf16x8*)&A_s[cur][w * 16 + lr][24 + kc * 32 + lg * 8];
        xacc = __builtin_amdgcn_mfma_f32_16x16x32_bf16(a, hb[kc], xacc, 0, 0, 0);
      }
      if (lr < 12) {
        #pragma unroll
        for (int r = 0; r < 4; ++r) xh_s[w * 16 + lg * 4 + r][lr] = xacc[r] + hbias;
      }
    }
    __syncthreads();

    // ---- S3a: loss1, x_c ----
    if (tid < BT * D_) {
      int b = tid & 31, i = tid >> 5;
      float xh = xh_s[b][i], xv = x_s[b][i], mv = m_s[b][i];
      lossAcc = fmaf(fabsf(xv - xh) * mv, dInv, lossAcc);
      xc_s[b][i] = fmaf(mv, xv - xh, xh);
    }
    __syncthreads();

    // ---- S3b: z_h, alpha, c_h, c_c, loss2+3 ----
    if (tid < BT * D_) {
      int b = tid & 31, i = tid >> 5;
      float zh = featb_s[i];
      #pragma unroll
      for (int k = 0; k < D_; ++k) zh = fmaf(xc_s[b][k], featW_s[i][k], zh);
      float xv = x_s[b][i], mv = m_s[b][i];
      lossAcc = fmaf(fabsf(xv - zh) * mv, dInv, lossAcc);
      float al = wcb_s[i];
      #pragma unroll
      for (int k = 0; k < D_; ++k) {
        al = fmaf(gx_s[b][k], wcW_s[i][k], al);
        al = fmaf(m_s[b][k], wcW_s[i][D_ + k], al);
      }
      float xh = xh_s[b][i];
      float ch = fmaf(al, zh - xh, xh);
      lossAcc = fmaf(fabsf(xv - ch) * mv, dInv, lossAcc);
      float cc = fmaf(mv, xv - ch, ch);
      cct_s[b][i] = cc;
      A_s[cur][b][i] = f2bf(cc);
    }
    __syncthreads();

    // ---- imputation store (overlapped with gate phase) ----
    if (tid < 96) {
      int b = tid / 3, q = tid % 3;
      float4 v = make_float4(cct_s[b][q * 4 + 0], cct_s[b][q * 4 + 1],
                             cct_s[b][q * 4 + 2], cct_s[b][q * 4 + 3]);
      *(float4*)(out_imp + ((size_t)(bs + b) * T_ + t) * D_ + q * 4) = v;
    }

    // ---- S5: gate GEMM via MFMA + LSTM pointwise ----
    {
      f32x4 acc[2][4];
      #pragma unroll
      for (int m = 0; m < 2; ++m)
        #pragma unroll
        for (int g = 0; g < 4; ++g) acc[m][g] = (f32x4){0.f, 0.f, 0.f, 0.f};
      #pragma unroll
      for (int kc = 0; kc < 5; ++kc) {
        const bf16x8 a0 = *(const bf16x8*)&A_s[cur][lr][kc * 32 + lg * 8];
        const bf16x8 a1 = *(const bf16x8*)&A_s[cur][16 + lr][kc * 32 + lg * 8];
        #pragma unroll
        for (int g = 0; g < 4; ++g) {
          acc[0][g] = __builtin_amdgcn_mfma_f32_16x16x32_bf16(a0, bq[g][kc], acc[0][g], 0, 0, 0);
          acc[1][g] = __builtin_amdgcn_mfma_f32_16x16x32_bf16(a1, bq[g][kc], acc[1][g], 0, 0, 0);
        }
      }
      const int jg = w * 16 + lr;
      #pragma unroll
      for (int m = 0; m < 2; ++m)
        #pragma unroll
        for (int r = 0; r < 4; ++r) {
          float gi = sigm(acc[m][0][r] + bj[0]);
          float gf = sigm(acc[m][1][r] + bj[1]);
          float gg = tanhc(acc[m][2][r] + bj[2]);
          float go = sigm(acc[m][3][r] + bj[3]);
          float c = fmaf(gf, c_st[m][r], gi * gg);
          c_st[m][r] = c;
          A_s[cur ^ 1][m * 16 + lg * 4 + r][24 + jg] = f2bf(go * tanhc(c));
        }
    }
    __syncthreads();
    cur ^= 1;
  }

  // ---- predictions ----
  if (tid < BT) {
    float a = outb_s;
    #pragma unroll 4
    for (int k = 0; k < H_; ++k) a = fmaf(bf2f(A_s[cur][tid][24 + k]), outW_s[k], a);
    out_pred[bs + tid] = sigm(a);
  }

  // ---- block loss reduce ----
  red_s[tid] = lossAcc;
  __syncthreads();
  for (int s = NTH / 2; s > 0; s >>= 1) { if (tid < s) red_s[tid] += red_s[tid + s]; __syncthreads(); }
  if (tid == 0) blockLoss[blockIdx.x] = red_s[0];
}

// ---------------- K2: final loss ----------------
__global__ void k_final(const float* __restrict__ blockLoss, float* __restrict__ out_loss) {
  __shared__ float r[256];
  int tid = threadIdx.x;
  r[tid] = blockLoss[tid] + blockLoss[tid + 256];
  __syncthreads();
  for (int s = 128; s > 0; s >>= 1) { if (tid < s) r[tid] += r[tid + s]; __syncthreads(); }
  if (tid == 0) out_loss[0] = r[0] * (1.f / (float)T_);
}

extern "C" void kernel_launch(void* const* d_in, const int* in_sizes, int n_in,
                              void* d_out, int out_size, void* d_ws, size_t ws_size,
                              hipStream_t stream) {
  const float* values = (const float*)d_in[0];
  const float* masks  = (const float*)d_in[1];
  const float* deltas = (const float*)d_in[2];
  const float* td_h_W = (const float*)d_in[3];
  const float* td_h_b = (const float*)d_in[4];
  const float* td_x_W = (const float*)d_in[5];
  const float* td_x_b = (const float*)d_in[6];
  const float* hist_W = (const float*)d_in[7];
  const float* hist_b = (const float*)d_in[8];
  const float* feat_W = (const float*)d_in[9];
  const float* feat_b = (const float*)d_in[10];
  const float* wc_W   = (const float*)d_in[11];
  const float* wc_b   = (const float*)d_in[12];
  const float* W_ih   = (const float*)d_in[13];
  const float* b_ih   = (const float*)d_in[14];
  const float* W_hh   = (const float*)d_in[15];
  const float* b_hh   = (const float*)d_in[16];
  const float* out_W  = (const float*)d_in[17];
  const float* out_b  = (const float*)d_in[18];

  float* ws_f      = (float*)d_ws;
  float* denomInv  = ws_f;            // 80 f32
  float* bias_pk   = ws_f + 128;      // 512 f32
  float* blockLoss = ws_f + 1024;     // 512 f32
  us_t* Wb   = (us_t*)(ws_f + 2048);  // 81920 bf16 (gate B-frags)
  us_t* histB = Wb + 81920;           // 2048 bf16

  float* out_f = (float*)d_out;       // [loss(1) | predictions(B) | imputations(B*T*D)]

  k_denom<<<T_, 256, 0, stream>>>(masks, denomInv);
  k_pack<<<330, 256, 0, stream>>>(W_ih, b_ih, W_hh, b_hh, hist_W, Wb, histB, bias_pk);
  k_main<<<NBLK, NTH, 0, stream>>>(values, masks, deltas, td_h_W, td_h_b, td_x_W, td_x_b,
                                   hist_b, feat_W, feat_b, wc_W, wc_b,
                                   out_W, out_b, denomInv, bias_pk, Wb, histB,
                                   blockLoss, out_f + 1, out_f + 1 + B_);
  k_final<<<1, 256, 0, stream>>>(blockLoss, out_f);
}

// Round 5
// 733.686 us; speedup vs baseline: 7.1969x; 1.2310x over previous
//
#include <hip/hip_runtime.h>

#define B_ 16384
#define T_ 80
#define D_ 12
#define H_ 128
#define BT 32            // batch rows per block
#define NTH 512          // 8 waves
#define NBLK (B_ / BT)   // 512

typedef unsigned short us_t;
typedef unsigned int u32_t;
typedef short bf16x8 __attribute__((ext_vector_type(8)));
typedef float f32x4 __attribute__((ext_vector_type(4)));

__device__ __forceinline__ us_t f2bf(float f){
  u32_t x = __float_as_uint(f);
  return (us_t)((x + 0x7FFFu + ((x >> 16) & 1u)) >> 16);   // RNE
}
__device__ __forceinline__ float bf2f(us_t u){
  union { u32_t i; float f; } v; v.i = ((u32_t)u) << 16; return v.f;
}
__device__ __forceinline__ float sigm(float x){ return 1.f / (1.f + __expf(-x)); }
__device__ __forceinline__ float tanhc(float x){
  x = fminf(fmaxf(x, -15.f), 15.f);
  float e = __expf(2.f * x);
  return (e - 1.f) / (e + 1.f);
}

// ---------------- K0a: per-step mask denominators ----------------
__global__ void k_denom(const float* __restrict__ masks, float* __restrict__ denomInv) {
  int t = blockIdx.x, tid = threadIdx.x;
  float s = 0.f;
  for (int b = tid; b < B_; b += 256) {
    const float4* p = (const float4*)(masks + ((size_t)b * T_ + t) * D_);
    float4 a = p[0], c = p[1], d = p[2];
    s += a.x + a.y + a.z + a.w + c.x + c.y + c.z + c.w + d.x + d.y + d.z + d.w;
  }
  __shared__ float r[256];
  r[tid] = s; __syncthreads();
  for (int st = 128; st > 0; st >>= 1) { if (tid < st) r[tid] += r[tid + st]; __syncthreads(); }
  if (tid == 0) denomInv[t] = 1.f / (r[0] + 1e-5f);
}

// ---------------- K0b: pack B-fragments (bf16) ----------------
// Wb: gate weights, combined K (0..12 c_c -> W_ih, 12..24 m -> W_ih, 24..152 h -> W_hh, pad)
// histB: hist_W fragged; tdhwB: td_h_W fragged (K=12 pad 32); bias_pk = b_ih+b_hh
__global__ void k_pack(const float* __restrict__ W_ih, const float* __restrict__ W_hh,
                       const float* __restrict__ hist_W, const float* __restrict__ td_h_W,
                       const float* __restrict__ b_ih, const float* __restrict__ b_hh,
                       us_t* __restrict__ Wb, us_t* __restrict__ histB,
                       us_t* __restrict__ tdhwB, float* __restrict__ bias_pk) {
  int idx = blockIdx.x * 256 + threadIdx.x;
  if (idx < 81920) {
    int i = idx & 7, lane = (idx >> 3) & 63, rest = idx >> 9;
    int kc = rest % 5; rest /= 5;
    int g = rest & 3, w = rest >> 2;
    int n = g * 128 + w * 16 + (lane & 15);
    int k = kc * 32 + ((lane >> 4) << 3) + i;
    float v = 0.f;
    if (k < 24) v = W_ih[n * 24 + k];
    else if (k < 152) v = W_hh[n * 128 + (k - 24)];
    Wb[idx] = f2bf(v);
  } else if (idx < 83968) {
    int e = idx - 81920;
    int i = e & 7, lane = (e >> 3) & 63, kc = e >> 9;
    int col = lane & 15, k = kc * 32 + ((lane >> 4) << 3) + i;
    histB[e] = f2bf(col < 12 ? hist_W[col * 128 + k] : 0.f);
  } else if (idx < 88064) {
    int e = idx - 83968;
    int i = e & 7, lane = (e >> 3) & 63, w = e >> 9;
    int n = w * 16 + (lane & 15), k = ((lane >> 4) << 3) + i;
    tdhwB[e] = f2bf(k < 12 ? td_h_W[n * 12 + k] : 0.f);
  } else if (idx < 88576) {
    int e = idx - 88064;
    bias_pk[e] = b_ih[e] + b_hh[e];
  }
}

// staging writes from held register float4 (loader threads)
#define STAGE_WRITE(BUF, V) do { \
  if (la == 0) { \
    x_s[lb][lq*4+0] = (V).x; x_s[lb][lq*4+1] = (V).y; \
    x_s[lb][lq*4+2] = (V).z; x_s[lb][lq*4+3] = (V).w; \
  } else if (la == 1) { \
    m_s[lb][lq*4+0] = (V).x; m_s[lb][lq*4+1] = (V).y; \
    m_s[lb][lq*4+2] = (V).z; m_s[lb][lq*4+3] = (V).w; \
    float _mv0=(V).x,_mv1=(V).y,_mv2=(V).z,_mv3=(V).w; \
    int _k = 12 + lq*4; \
    A_s[BUF][(_k+0)>>3][lb][(_k+0)&7] = f2bf(_mv0); \
    A_s[BUF][(_k+1)>>3][lb][(_k+1)&7] = f2bf(_mv1); \
    A_s[BUF][(_k+2)>>3][lb][(_k+2)&7] = f2bf(_mv2); \
    A_s[BUF][(_k+3)>>3][lb][(_k+3)&7] = f2bf(_mv3); \
  } else { \
    float _dv[4] = {(V).x,(V).y,(V).z,(V).w}; \
    _Pragma("unroll") \
    for (int _j = 0; _j < 4; ++_j) { \
      int _i = lq*4+_j; \
      gx_s[lb][_i] = __expf(-fmaxf(fmaf(_dv[_j], tdxd_s[_i], tdxb_s[_i]), 0.f)); \
      dA_s[_i>>3][lb][_i&7] = f2bf(_dv[_j]); \
    } \
  } \
} while(0)

// ---------------- K1: main recurrence ----------------
__global__ __launch_bounds__(NTH) void k_main(
    const float* __restrict__ values, const float* __restrict__ masks, const float* __restrict__ deltas,
    const float* __restrict__ td_h_b, const float* __restrict__ td_x_W, const float* __restrict__ td_x_b,
    const float* __restrict__ hist_b, const float* __restrict__ feat_W, const float* __restrict__ feat_b,
    const float* __restrict__ wc_W, const float* __restrict__ wc_b,
    const float* __restrict__ out_W, const float* __restrict__ out_b,
    const float* __restrict__ denomInv, const float* __restrict__ bias_pk,
    const us_t* __restrict__ Wb, const us_t* __restrict__ histB, const us_t* __restrict__ tdhwB,
    float* __restrict__ blockLoss, float* __restrict__ out_pred, float* __restrict__ out_imp) {

  // A tile in [kgrp][row][8] subtiles: gate-K = {c_c 0..12, m 12..24, h 24..152, pad ..160}
  __shared__ __align__(16) us_t A_s[2][20][BT][8];
  __shared__ __align__(16) us_t dA_s[4][BT][8];        // d(t+1), K pad 32
  __shared__ __align__(16) us_t histB_s[4][64][8];
  __shared__ float x_s[BT][13], m_s[BT][13], gx_s[BT][13], cct_s[BT][13], xh_s[BT][13];
  __shared__ float featW_s[12][12], wcW_s[12][24];
  __shared__ float featb_s[12], wcb_s[12], tdxd_s[12], tdxb_s[12];
  __shared__ float outW_s[128];
  __shared__ float outb_s;
  __shared__ float red_s[NTH];

  const int tid = threadIdx.x;
  const int bs = blockIdx.x * BT;
  const int w = tid >> 6, l = tid & 63;
  const int lr = l & 15, lg = l >> 4;

  // ---- one-time init ----
  for (int i = tid; i < 144; i += NTH)
    featW_s[i / 12][i % 12] = ((i / 12) == (i % 12)) ? 0.f : feat_W[i];
  for (int i = tid; i < 288; i += NTH) ((float*)wcW_s)[i] = wc_W[i];
  if (tid < 12) {
    featb_s[tid] = feat_b[tid]; wcb_s[tid] = wc_b[tid];
    tdxd_s[tid] = td_x_W[tid * 12 + tid]; tdxb_s[tid] = td_x_b[tid];
  }
  if (tid < 128) outW_s[tid] = out_W[tid];
  if (tid == 0) outb_s = out_b[0];
  for (int i = tid; i < 2 * 20 * BT * 8; i += NTH) ((us_t*)A_s)[i] = 0;
  for (int i = tid; i < 4 * BT * 8; i += NTH) ((us_t*)dA_s)[i] = 0;
  for (int i = tid; i < 2048; i += NTH) ((us_t*)histB_s)[i] = histB[i];

  // ---- persistent registers ----
  bf16x8 bq[4][5];
  #pragma unroll
  for (int g = 0; g < 4; ++g)
    #pragma unroll
    for (int kc = 0; kc < 5; ++kc)
      bq[g][kc] = *(const bf16x8*)(Wb + (size_t)((((w * 4 + g) * 5 + kc) * 64 + l) << 3));
  const bf16x8 twf = *(const bf16x8*)(tdhwB + (size_t)(((w * 64) + l) << 3));
  float bj[4];
  #pragma unroll
  for (int g = 0; g < 4; ++g) bj[g] = bias_pk[g * 128 + w * 16 + lr];
  const float tdhb_j = td_h_b[w * 16 + lr];
  const float hbias = hist_b[lr < 12 ? lr : 0];

  // loader roles: threads [128,416) load one float4 of {x,m,d}(t+1)
  const int lt = tid - 128;
  const bool isLoader = (lt >= 0 && lt < 288);
  const int la = isLoader ? lt / 96 : 0;
  const int lrm = isLoader ? lt % 96 : 0;
  const int lb = lrm / 3, lq = lrm % 3;
  const float* lsrc = (la == 0) ? values : (la == 1) ? masks : deltas;

  float c_st[2][4] = {{0.f,0.f,0.f,0.f},{0.f,0.f,0.f,0.f}};
  float lossAcc = 0.f;
  int cur = 0;
  __syncthreads();

  // ---- prime t=0 staging ----
  if (isLoader) {
    float4 pv = *(const float4*)(lsrc + ((size_t)(bs + lb) * T_) * D_ + lq * 4);
    STAGE_WRITE(0, pv);
  }
  __syncthreads();

  for (int t = 0; t < T_; ++t) {
    const float dInv = denomInv[t];
    float4 ldv;

    // ---- P1: x_h MFMA (waves 0-1) | issue t+1 loads | imp store t-1 ----
    if (w < 2) {
      f32x4 xacc = {0.f, 0.f, 0.f, 0.f};
      #pragma unroll
      for (int kc = 0; kc < 4; ++kc) {
        const bf16x8 af = *(const bf16x8*)&A_s[cur][3 + kc * 4 + lg][w * 16 + lr][0];
        const bf16x8 hf = *(const bf16x8*)&histB_s[kc][l][0];
        xacc = __builtin_amdgcn_mfma_f32_16x16x32_bf16(af, hf, xacc, 0, 0, 0);
      }
      if (lr < 12) {
        #pragma unroll
        for (int r = 0; r < 4; ++r) xh_s[w * 16 + lg * 4 + r][lr] = xacc[r] + hbias;
      }
    } else if (isLoader) {
      if (t + 1 < T_)
        ldv = *(const float4*)(lsrc + ((size_t)(bs + lb) * T_ + (t + 1)) * D_ + lq * 4);
    } else if (t > 0) {   // tid in [416,512): 96 threads
      int ib = (tid - 416) / 3, iq = (tid - 416) % 3;
      float4 v = make_float4(cct_s[ib][iq * 4 + 0], cct_s[ib][iq * 4 + 1],
                             cct_s[ib][iq * 4 + 2], cct_s[ib][iq * 4 + 3]);
      *(float4*)(out_imp + ((size_t)(bs + ib) * T_ + (t - 1)) * D_ + iq * 4) = v;
    }
    __syncthreads();

    // ---- P2: merged small phase (384 threads, one per (b,i)) ----
    if (tid < 384) {
      int b = tid & 31, i = tid >> 5;
      float xh = xh_s[b][i], xv = x_s[b][i], mv = m_s[b][i];
      lossAcc = fmaf(fabsf(xv - xh) * mv, dInv, lossAcc);
      float zh = featb_s[i];
      #pragma unroll
      for (int k = 0; k < 12; ++k) {
        float xck = fmaf(m_s[b][k], x_s[b][k] - xh_s[b][k], xh_s[b][k]);
        zh = fmaf(xck, featW_s[i][k], zh);
      }
      lossAcc = fmaf(fabsf(xv - zh) * mv, dInv, lossAcc);
      float al = wcb_s[i];
      #pragma unroll
      for (int k = 0; k < 12; ++k) {
        al = fmaf(gx_s[b][k], wcW_s[i][k], al);
        al = fmaf(m_s[b][k], wcW_s[i][12 + k], al);
      }
      float ch = fmaf(al, zh - xh, xh);
      lossAcc = fmaf(fabsf(xv - ch) * mv, dInv, lossAcc);
      float cc = fmaf(mv, xv - ch, ch);
      cct_s[b][i] = cc;
      A_s[cur][i >> 3][b][i & 7] = f2bf(cc);
    }
    __syncthreads();

    // ---- P3: gate MFMA + stage t+1 into LDS ----
    {
      if (isLoader && (t + 1 < T_)) STAGE_WRITE(cur ^ 1, ldv);
      f32x4 acc[2][4];
      #pragma unroll
      for (int m = 0; m < 2; ++m)
        #pragma unroll
        for (int g = 0; g < 4; ++g) acc[m][g] = (f32x4){0.f, 0.f, 0.f, 0.f};
      #pragma unroll
      for (int kc = 0; kc < 5; ++kc) {
        const bf16x8 a0 = *(const bf16x8*)&A_s[cur][kc * 4 + lg][lr][0];
        const bf16x8 a1 = *(const bf16x8*)&A_s[cur][kc * 4 + lg][16 + lr][0];
        #pragma unroll
        for (int g = 0; g < 4; ++g) {
          acc[0][g] = __builtin_amdgcn_mfma_f32_16x16x32_bf16(a0, bq[g][kc], acc[0][g], 0, 0, 0);
          acc[1][g] = __builtin_amdgcn_mfma_f32_16x16x32_bf16(a1, bq[g][kc], acc[1][g], 0, 0, 0);
        }
      }
      __syncthreads();   // C2: dA_s(t+1) ready

      // ---- P4: gamma MFMA (C-layout == gate C-layout) + epilogue ----
      f32x4 g0 = {0.f,0.f,0.f,0.f}, g1 = {0.f,0.f,0.f,0.f};
      const bf16x8 d0 = *(const bf16x8*)&dA_s[lg][lr][0];
      const bf16x8 d1 = *(const bf16x8*)&dA_s[lg][16 + lr][0];
      g0 = __builtin_amdgcn_mfma_f32_16x16x32_bf16(d0, twf, g0, 0, 0, 0);
      g1 = __builtin_amdgcn_mfma_f32_16x16x32_bf16(d1, twf, g1, 0, 0, 0);
      const bool dec = (t + 1 < T_);
      const int kgh = 3 + 2 * w + (lr >> 3), pgh = lr & 7;
      #pragma unroll
      for (int m = 0; m < 2; ++m) {
        #pragma unroll
        for (int r = 0; r < 4; ++r) {
          float gi = sigm(acc[m][0][r] + bj[0]);
          float gf = sigm(acc[m][1][r] + bj[1]);
          float gg = tanhc(acc[m][2][r] + bj[2]);
          float go = sigm(acc[m][3][r] + bj[3]);
          float c = fmaf(gf, c_st[m][r], gi * gg);
          c_st[m][r] = c;
          float hn = go * tanhc(c);
          float pre = (m == 0 ? g0[r] : g1[r]) + tdhb_j;
          float gh = dec ? __expf(-fmaxf(pre, 0.f)) : 1.f;
          A_s[cur ^ 1][kgh][m * 16 + lg * 4 + r][pgh] = f2bf(hn * gh);
        }
      }
    }
    __syncthreads();
    cur ^= 1;
  }

  // ---- final imputation (t = T-1) ----
  if (tid >= 416) {
    int ib = (tid - 416) / 3, iq = (tid - 416) % 3;
    float4 v = make_float4(cct_s[ib][iq * 4 + 0], cct_s[ib][iq * 4 + 1],
                           cct_s[ib][iq * 4 + 2], cct_s[ib][iq * 4 + 3]);
    *(float4*)(out_imp + ((size_t)(bs + ib) * T_ + (T_ - 1)) * D_ + iq * 4) = v;
  }

  // ---- predictions (raw final h; no decay applied at t=T-1) ----
  if (tid < BT) {
    float a = outb_s;
    #pragma unroll 4
    for (int k = 0; k < H_; ++k)
      a = fmaf(bf2f(A_s[cur][3 + (k >> 3)][tid][k & 7]), outW_s[k], a);
    out_pred[bs + tid] = sigm(a);
  }

  // ---- block loss reduce ----
  red_s[tid] = lossAcc;
  __syncthreads();
  for (int s = NTH / 2; s > 0; s >>= 1) { if (tid < s) red_s[tid] += red_s[tid + s]; __syncthreads(); }
  if (tid == 0) blockLoss[blockIdx.x] = red_s[0];
}

// ---------------- K2: final loss ----------------
__global__ void k_final(const float* __restrict__ blockLoss, float* __restrict__ out_loss) {
  __shared__ float r[256];
  int tid = threadIdx.x;
  r[tid] = blockLoss[tid] + blockLoss[tid + 256];
  __syncthreads();
  for (int s = 128; s > 0; s >>= 1) { if (tid < s) r[tid] += r[tid + s]; __syncthreads(); }
  if (tid == 0) out_loss[0] = r[0] * (1.f / (float)T_);
}

extern "C" void kernel_launch(void* const* d_in, const int* in_sizes, int n_in,
                              void* d_out, int out_size, void* d_ws, size_t ws_size,
                              hipStream_t stream) {
  const float* values = (const float*)d_in[0];
  const float* masks  = (const float*)d_in[1];
  const float* deltas = (const float*)d_in[2];
  const float* td_h_W = (const float*)d_in[3];
  const float* td_h_b = (const float*)d_in[4];
  const float* td_x_W = (const float*)d_in[5];
  const float* td_x_b = (const float*)d_in[6];
  const float* hist_W = (const float*)d_in[7];
  const float* hist_b = (const float*)d_in[8];
  const float* feat_W = (const float*)d_in[9];
  const float* feat_b = (const float*)d_in[10];
  const float* wc_W   = (const float*)d_in[11];
  const float* wc_b   = (const float*)d_in[12];
  const float* W_ih   = (const float*)d_in[13];
  const float* b_ih   = (const float*)d_in[14];
  const float* W_hh   = (const float*)d_in[15];
  const float* b_hh   = (const float*)d_in[16];
  const float* out_W  = (const float*)d_in[17];
  const float* out_b  = (const float*)d_in[18];

  float* ws_f      = (float*)d_ws;
  float* denomInv  = ws_f;            // 80 f32
  float* bias_pk   = ws_f + 128;      // 512 f32
  float* blockLoss = ws_f + 1024;     // 512 f32
  us_t* Wb    = (us_t*)(ws_f + 2048); // 81920 bf16
  us_t* histB = Wb + 81920;           // 2048 bf16
  us_t* tdhwB = histB + 2048;         // 4096 bf16

  float* out_f = (float*)d_out;       // [loss(1) | predictions(B) | imputations(B*T*D)]

  k_denom<<<T_, 256, 0, stream>>>(masks, denomInv);
  k_pack<<<346, 256, 0, stream>>>(W_ih, W_hh, hist_W, td_h_W, b_ih, b_hh,
                                  Wb, histB, tdhwB, bias_pk);
  k_main<<<NBLK, NTH, 0, stream>>>(values, masks, deltas, td_h_b, td_x_W, td_x_b,
                                   hist_b, feat_W, feat_b, wc_W, wc_b,
                                   out_W, out_b, denomInv, bias_pk, Wb, histB, tdhwB,
                                   blockLoss, out_f + 1, out_f + 1 + B_);
  k_final<<<1, 256, 0, stream>>>(blockLoss, out_f);
}